// Round 10
// baseline (548.650 us; speedup 1.0000x reference)
//
#include <hip/hip_runtime.h>
#include <hip/hip_bf16.h>

// B=2, S=1024, D=2048, NH=8, dqk=128, dv=256, I=8192
#define TOKENS 2048
#define DMODEL 2048
#define SEQ    1024

typedef __attribute__((ext_vector_type(8))) short bf16x8;
typedef __attribute__((ext_vector_type(4))) short bf16x4;
typedef __attribute__((ext_vector_type(4))) float f32x4;
typedef __attribute__((ext_vector_type(8))) unsigned short u16x8;
typedef __attribute__((ext_vector_type(4))) unsigned short u16x4;

__device__ __forceinline__ float sigmoidf_(float x) { return 1.f / (1.f + expf(-x)); }
__device__ __forceinline__ float softcapf_(float x) { return 15.f * tanhf(x * (1.f / 15.f)); }
__device__ __forceinline__ float logsigf_(float x) {
  return (x >= 0.f) ? -log1pf(expf(-x)) : (x - log1pf(expf(x)));
}
__device__ __forceinline__ unsigned short f2bf(float f) {  // RNE, inputs finite
  unsigned u = __builtin_bit_cast(unsigned, f);
  u += 0x7FFFu + ((u >> 16) & 1u);
  return (unsigned short)(u >> 16);
}
__device__ __forceinline__ float bf2f(unsigned short b) {
  unsigned u = ((unsigned)b) << 16;
  return __builtin_bit_cast(float, u);
}

typedef __attribute__((address_space(3))) void lds_void;
typedef const __attribute__((address_space(1))) void gmem_void;
__device__ __forceinline__ void gload16(const void* g, void* l) {
  __builtin_amdgcn_global_load_lds((gmem_void*)g, (lds_void*)l, 16, 0, 0);
}
__device__ __forceinline__ unsigned lds_off(const void* p) {
  return (unsigned)(size_t)(__attribute__((address_space(3))) const void*)p;
}

#if defined(__has_builtin)
#if __has_builtin(__builtin_amdgcn_mfma_f32_16x16x16bf16_1k)
#define HAVE_MFMA16 1
#endif
#endif

__device__ __forceinline__ f32x4 mfma16_bf16(bf16x4 a, bf16x4 b, f32x4 c) {
#ifdef HAVE_MFMA16
  return __builtin_amdgcn_mfma_f32_16x16x16bf16_1k(a, b, c, 0, 0, 0);
#else
  f32x4 d;
  asm volatile("v_mfma_f32_16x16x16_bf16 %0, %1, %2, %3"
               : "=v"(d) : "v"(a), "v"(b), "v"(c));
  return d;
#endif
}

__device__ __forceinline__ bf16x4 tr_read(unsigned addr) {
  bf16x4 d;
  asm volatile("ds_read_b64_tr_b16 %0, %1" : "=v"(d) : "v"(addr));
  return d;
}

// XCD-chunked (T1) + M-fastest rasterization. Requires gridDim.x*y % 8 == 0.
__device__ __forceinline__ void remap_block(int& bm, int& bn) {
  const int nbx = gridDim.x, nby = gridDim.y;
  const int bid = blockIdx.y * nbx + blockIdx.x;
  const int q = (nbx * nby) >> 3;
  const int lid = (bid & 7) * q + (bid >> 3);
  bm = lid % nby;
  bn = lid / nby;
}

// ---------------------------------------------------------------------------
// 256x256-tile bf16 MFMA GEMM — 8-phase schedule (T2+T3+T4+T5, m201 port):
// C[M,N] = A[M,K(ldk)] @ BT[N,K(ldk)]^T. BK=64 per K-tile, 4 phases/tile.
// 512 thr = 8 waves (2Mx4N), acc[8][4] (128x64/wave). LDS 128 KiB = 2 bufs x
// {A.k0,A.k1,B.k0,B.k1} of 256x32 bf16 each.
// STAGING RESPECTS THE global_load_lds HW RULE (m104/m108): per instruction,
// LDS dest = wave-uniform base + lane*16B. Instruction 0 covers rows 0..127
// (elements [tid*8, tid*8+8)), instruction 1 rows 128..255 (+4096 elements).
// Swizzle: LDS chunk c of row r holds global chunk c^((r+(r>>2))&3); applied
// via pre-swizzled SOURCE + same XOR on the read (both-sides involution).
// Per phase: {ds_read frags | stage 1 half-tile -> barrier -> 16 MFMA
// (setprio) -> barrier}. ONE counted vmcnt(6) per K-tile (3 half-tiles stay
// in flight; never drained to 0 until the final tile).
// EPI 0: fp32 out at Cout + z*M*N (split-K). EPI 1: bf16.
// EPI 2: bf16 silu(aux)*acc. EPI 4: qkvo split (2048-col panels).
// ---------------------------------------------------------------------------
template <int EPI>
__global__ __launch_bounds__(512) void gemm256(
    const unsigned short* __restrict__ A, const unsigned short* __restrict__ BT,
    void* __restrict__ Cout, void* __restrict__ Cout2, void* __restrict__ Cout3,
    const unsigned short* __restrict__ aux, int M, int N, int K, int ldk) {
  __shared__ unsigned short sh[65536];  // 128 KiB: [buf][part][256*32]
  const int tid = threadIdx.x;
  int bm, bn;
  remap_block(bm, bn);
  const int m0 = bm * 256, n0 = bn * 256;
  const int wid = tid >> 6, lane = tid & 63;
  const int wr = wid >> 2, wc = wid & 3;  // 2 x 4 waves
  const int fr = lane & 15, fq = lane >> 4;
  const size_t kz = (size_t)blockIdx.z * K;

  const f32x4 zero = {0.f, 0.f, 0.f, 0.f};
  f32x4 acc[8][4];
#pragma unroll
  for (int m = 0; m < 8; ++m)
#pragma unroll
    for (int n = 0; n < 4; ++n) acc[m][n] = zero;

  // staging addressing (lane*16B rule): thread covers rows sr and sr+128,
  // chunk sc; source chunk pre-swizzled.
  const int sr = tid >> 2;
  const int sc = tid & 3;
  const int swz = (sr + (sr >> 2)) & 3;
  const unsigned short* pA = A + kz + (size_t)(m0 + sr) * ldk + (sc ^ swz) * 8;
  const unsigned short* pB = BT + kz + (size_t)(n0 + sr) * ldk + (sc ^ swz) * 8;
  const size_t hstep = (size_t)128 * ldk;

  // parts: 0=A.k0, 1=A.k1, 2=B.k0, 3=B.k1 (each 8192 elements = 16 KB)
  auto stage = [&](int th, int part) {
    unsigned short* d = &sh[((th & 1) << 15) + (part << 13) + tid * 8];
    const size_t ko = (size_t)th * 64 + ((part & 1) << 5);
    if (part < 2) {
      gload16(pA + ko, d);
      gload16(pA + ko + hstep, d + 4096);
    } else {
      gload16(pB + ko, d);
      gload16(pB + ko + hstep, d + 4096);
    }
  };

  // read offsets (lane-constant swizzled chunk; row%4 == fr%4 for all frags)
  const int rsw = (fq ^ ((fr + (fr >> 2)) & 3)) * 8;
  const int aoff = (wr * 128 + fr) * 32 + rsw;
  const int boff = (wc * 64 + fr) * 32 + rsw;

  auto lda = [&](int buf, int kh, int mq, bf16x8* af) {
    const unsigned short* p = &sh[(buf << 15) + (kh << 13) + aoff + (mq << 11)];
#pragma unroll
    for (int m = 0; m < 4; ++m) af[m] = *(const bf16x8*)(p + m * 512);
  };
  auto ldb = [&](int buf, int kh, bf16x8* bfm) {
    const unsigned short* p = &sh[(buf << 15) + 16384 + (kh << 13) + boff];
#pragma unroll
    for (int n = 0; n < 4; ++n) bfm[n] = *(const bf16x8*)(p + n * 512);
  };

  bf16x8 af[4], bfm[4];
  auto domfma = [&](int mq) {
    __builtin_amdgcn_s_setprio(1);
#pragma unroll
    for (int m = 0; m < 4; ++m)
#pragma unroll
      for (int n = 0; n < 4; ++n)
        acc[mq * 4 + m][n] = __builtin_amdgcn_mfma_f32_16x16x32_bf16(
            af[m], bfm[n], acc[mq * 4 + m][n], 0, 0, 0);
    __builtin_amdgcn_s_setprio(0);
  };

  const int NT = K >> 6;  // >= 2 for all uses (K >= 2048)
  // prologue: tile0 all 4 halves, then tile1 k0-halves
  stage(0, 0); stage(0, 2); stage(0, 1); stage(0, 3);
  stage(1, 0); stage(1, 2);

  for (int T = 0; T < NT; ++T) {
    const int buf = T & 1;
    // ---- phase 0 (kh0, mq0) — tile boundary
    if (T + 1 < NT) stage(T + 1, 1);  // A.k1 -> other buf (dead since T-1)
    if (T + 1 < NT) {
      asm volatile("s_waitcnt vmcnt(6)" ::: "memory");
    } else {
      asm volatile("s_waitcnt vmcnt(0)" ::: "memory");
    }
    __builtin_amdgcn_s_barrier();
    __builtin_amdgcn_sched_barrier(0);
    ldb(buf, 0, bfm);
    lda(buf, 0, 0, af);
    domfma(0);
    __builtin_amdgcn_s_barrier();
    // ---- phase 1 (kh0, mq1)
    lda(buf, 0, 1, af);
    if (T + 1 < NT) stage(T + 1, 3);  // B.k1 -> other buf
    __builtin_amdgcn_s_barrier();
    domfma(1);
    __builtin_amdgcn_s_barrier();
    // ---- phase 2 (kh1, mq0)
    ldb(buf, 1, bfm);
    lda(buf, 1, 0, af);
    if (T + 2 < NT) stage(T + 2, 0);  // A.k0 -> THIS buf (dead after ph1)
    __builtin_amdgcn_s_barrier();
    domfma(0);
    __builtin_amdgcn_s_barrier();
    // ---- phase 3 (kh1, mq1)
    lda(buf, 1, 1, af);
    if (T + 2 < NT) stage(T + 2, 2);  // B.k0 -> THIS buf (dead after ph1)
    __builtin_amdgcn_s_barrier();
    domfma(1);
    __builtin_amdgcn_s_barrier();
  }

  const int orow = m0 + wr * 128 + fq * 4;
  const int ocol = n0 + wc * 64 + fr;
#pragma unroll
  for (int m = 0; m < 8; ++m) {
#pragma unroll
    for (int n = 0; n < 4; ++n) {
      const int cc = ocol + n * 16;
#pragma unroll
      for (int j = 0; j < 4; ++j) {
        const int r = orow + m * 16 + j;
        float v = acc[m][n][j];
        if (EPI == 0) {
          ((float*)Cout + (size_t)blockIdx.z * M * N)[(size_t)r * N + cc] = v;
        } else if (EPI == 1) {
          ((unsigned short*)Cout)[(size_t)r * N + cc] = f2bf(v);
        } else if (EPI == 2) {
          const size_t idx = (size_t)r * N + cc;
          const float gv = bf2f(aux[idx]);
          ((unsigned short*)Cout)[idx] = f2bf(v * gv * sigmoidf_(gv));
        } else {  // EPI 4: qkvo split
          if (cc < 2048)
            ((unsigned short*)Cout)[(size_t)r * 2048 + cc] = f2bf(v);
          else if (cc < 4096)
            ((unsigned short*)Cout2)[(size_t)r * 2048 + cc - 2048] = f2bf(v);
          else
            ((float*)Cout3)[(size_t)r * 2048 + cc - 4096] = v;
        }
      }
    }
  }
}

// ---------------------------------------------------------------------------
// 128x128-tile bf16 GEMM (2-phase dbuf + swizzle) — for attn projection.
// EPI 0: fp32 out. EPI 1: bf16 out.
// ---------------------------------------------------------------------------
template <int EPI>
__global__ __launch_bounds__(256) void gemm_bf16(
    const unsigned short* __restrict__ A, const unsigned short* __restrict__ BT,
    void* __restrict__ Cout, int M, int N, int K) {
  __shared__ unsigned short As[2][128 * 32];
  __shared__ unsigned short Bs[2][128 * 32];
  const int tid = threadIdx.x;
  int bm, bn;
  remap_block(bm, bn);
  const int m0 = bm * 128;
  const int n0 = bn * 128;
  const int wid = tid >> 6;
  const int lane = tid & 63;
  const int wr = wid >> 1, wc = wid & 1;
  const int fr = lane & 15, fq = lane >> 4;

  const f32x4 zero = {0.f, 0.f, 0.f, 0.f};
  f32x4 acc[4][4];
#pragma unroll
  for (int m = 0; m < 4; ++m)
#pragma unroll
    for (int n = 0; n < 4; ++n) acc[m][n] = zero;

  const int srow = tid >> 2;
  const int sc = tid & 3;
  const int sgc = sc ^ ((srow + (srow >> 2)) & 3);
  const int scol = sgc * 8;
  const unsigned short* Ag0 = A + (size_t)(m0 + srow) * K + scol;
  const unsigned short* Ag1 = A + (size_t)(m0 + 64 + srow) * K + scol;
  const unsigned short* Bg0 = BT + (size_t)(n0 + srow) * K + scol;
  const unsigned short* Bg1 = BT + (size_t)(n0 + 64 + srow) * K + scol;
  const int rsw = (fq ^ ((fr + (fr >> 2)) & 3)) * 8;

  gload16(Ag0, &As[0][tid * 8]);
  gload16(Ag1, &As[0][2048 + tid * 8]);
  gload16(Bg0, &Bs[0][tid * 8]);
  gload16(Bg1, &Bs[0][2048 + tid * 8]);
  __syncthreads();

  const int nt = K >> 5;
  for (int t = 0; t < nt; ++t) {
    const int cur = t & 1;
    if (t + 1 < nt) {
      const int k0 = (t + 1) << 5;
      gload16(Ag0 + k0, &As[cur ^ 1][tid * 8]);
      gload16(Ag1 + k0, &As[cur ^ 1][2048 + tid * 8]);
      gload16(Bg0 + k0, &Bs[cur ^ 1][tid * 8]);
      gload16(Bg1 + k0, &Bs[cur ^ 1][2048 + tid * 8]);
    }
    bf16x8 af[4], bfm[4];
#pragma unroll
    for (int m = 0; m < 4; ++m)
      af[m] = *(const bf16x8*)&As[cur][(wr * 64 + m * 16 + fr) * 32 + rsw];
#pragma unroll
    for (int n = 0; n < 4; ++n)
      bfm[n] = *(const bf16x8*)&Bs[cur][(wc * 64 + n * 16 + fr) * 32 + rsw];
    __builtin_amdgcn_s_setprio(1);
#pragma unroll
    for (int m = 0; m < 4; ++m)
#pragma unroll
      for (int n = 0; n < 4; ++n)
        acc[m][n] = __builtin_amdgcn_mfma_f32_16x16x32_bf16(af[m], bfm[n],
                                                            acc[m][n], 0, 0, 0);
    __builtin_amdgcn_s_setprio(0);
    __syncthreads();
  }

  const int orow = m0 + wr * 64 + fq * 4;
  const int ocol = n0 + wc * 64 + fr;
#pragma unroll
  for (int m = 0; m < 4; ++m) {
#pragma unroll
    for (int n = 0; n < 4; ++n) {
      const int cc = ocol + n * 16;
#pragma unroll
      for (int j = 0; j < 4; ++j) {
        const int r = orow + m * 16 + j;
        float v = acc[m][n][j];
        if (EPI == 0) ((float*)Cout)[(size_t)r * N + cc] = v;
        else ((unsigned short*)Cout)[(size_t)r * N + cc] = f2bf(v);
      }
    }
  }
}

// ---------------------------------------------------------------------------
// fp32 -> bf16 flat cast
// ---------------------------------------------------------------------------
__global__ __launch_bounds__(256) void castf2b_kernel(
    const float* __restrict__ in, unsigned short* __restrict__ outp) {
  const size_t i = ((size_t)blockIdx.x * 256 + threadIdx.x) * 8;
  float4 a = *(const float4*)&in[i];
  float4 b = *(const float4*)&in[i + 4];
  u16x8 o;
  o[0] = f2bf(a.x); o[1] = f2bf(a.y); o[2] = f2bf(a.z); o[3] = f2bf(a.w);
  o[4] = f2bf(b.x); o[5] = f2bf(b.y); o[6] = f2bf(b.z); o[7] = f2bf(b.w);
  *(u16x8*)&outp[i] = o;
}

// ---------------------------------------------------------------------------
// fp32 [K][N] -> bf16 [N][K] transpose-cast. 64K x 32N tiles; writes are
// 128B-contiguous row segments (u16x8/thread). K%64==0, N%32==0.
// ---------------------------------------------------------------------------
__global__ __launch_bounds__(256) void castT_kernel(
    const float* __restrict__ W, unsigned short* __restrict__ WT, int K, int N) {
  __shared__ float tile[64][33];
  const int n0 = blockIdx.x * 32, k0 = blockIdx.y * 64;
  const int r = threadIdx.x >> 3;        // 0..31
  const int c4 = (threadIdx.x & 7) * 4;  // 0..28
  float4 v0 = *(const float4*)&W[(size_t)(k0 + r) * N + n0 + c4];
  float4 v1 = *(const float4*)&W[(size_t)(k0 + 32 + r) * N + n0 + c4];
  tile[r][c4 + 0] = v0.x; tile[r][c4 + 1] = v0.y;
  tile[r][c4 + 2] = v0.z; tile[r][c4 + 3] = v0.w;
  tile[r + 32][c4 + 0] = v1.x; tile[r + 32][c4 + 1] = v1.y;
  tile[r + 32][c4 + 2] = v1.z; tile[r + 32][c4 + 3] = v1.w;
  __syncthreads();
  const int n = threadIdx.x >> 3;        // output row 0..31
  const int kc = (threadIdx.x & 7) * 8;  // k chunk
  u16x8 o;
#pragma unroll
  for (int j = 0; j < 8; ++j) o[j] = f2bf(tile[kc + j][n]);
  *(u16x8*)&WT[(size_t)(n0 + n) * K + k0 + kc] = o;
}

// ---------------------------------------------------------------------------
// [Wi|Wf] (each [2048][8] fp32) -> WT[16][2048] fp32 (rows: isF*8+head)
// ---------------------------------------------------------------------------
__global__ __launch_bounds__(256) void gatesT_kernel(
    const float* __restrict__ Wi, const float* __restrict__ Wf,
    float* __restrict__ WT) {
  const int idx = blockIdx.x * 256 + threadIdx.x;  // 0..32767
  const int row = idx >> 11;                       // 0..15
  const int d = idx & 2047;
  const float* W = (row < 8) ? Wi : Wf;
  WT[idx] = W[d * 8 + (row & 7)];
}

// ---------------------------------------------------------------------------
// Gate pre-activations (fp32), coalesced via WT[16][2048]
// ---------------------------------------------------------------------------
__global__ __launch_bounds__(256) void gates_kernel(
    const float* __restrict__ x, const float* __restrict__ WT,
    const float* __restrict__ bi, const float* __restrict__ bf,
    float* __restrict__ icap, float* __restrict__ fls) {
  const int t = blockIdx.x;
  const int tid = threadIdx.x;
  __shared__ float xs[2048];
  *(float4*)&xs[tid * 4] = *(const float4*)&x[(size_t)t * 2048 + tid * 4];
  *(float4*)&xs[1024 + tid * 4] =
      *(const float4*)&x[(size_t)t * 2048 + 1024 + tid * 4];
  __syncthreads();
  const int wave = tid >> 6, lane = tid & 63;
  const int b = t >> 10, s = t & 1023;
  for (int gg = wave; gg < 16; gg += 4) {
    const int head = gg & 7;
    const int isF = gg >> 3;
    const float* Wrow = WT + (size_t)gg * 2048;
    float acc = 0.f;
#pragma unroll
    for (int it = 0; it < 8; ++it) {
      const float4 w4 = *(const float4*)&Wrow[it * 256 + lane * 4];
      const float4 x4 = *(const float4*)&xs[it * 256 + lane * 4];
      acc = fmaf(x4.x, w4.x, acc);
      acc = fmaf(x4.y, w4.y, acc);
      acc = fmaf(x4.z, w4.z, acc);
      acc = fmaf(x4.w, w4.w, acc);
    }
#pragma unroll
    for (int m = 32; m > 0; m >>= 1) acc += __shfl_down(acc, m, 64);
    if (lane == 0) {
      const size_t o = (size_t)(b * 8 + head) * 1024 + s;
      if (isF) fls[o] = logsigf_(softcapf_(acc + bf[head]));
      else icap[o] = softcapf_(acc + bi[head]);
    }
  }
}

// ---------------------------------------------------------------------------
// Per-(b,h) scans: lfc = cumsum(fls); g = icap - lfc; mx = cummax(g)
// ---------------------------------------------------------------------------
__global__ __launch_bounds__(1024) void scan_kernel(
    const float* __restrict__ icap, const float* __restrict__ fls,
    float* __restrict__ lfc, float* __restrict__ garr, float* __restrict__ mx) {
  const int bh = blockIdx.x;
  const int tid = threadIdx.x;
  __shared__ float sm[1024];
  sm[tid] = fls[(size_t)bh * 1024 + tid];
  __syncthreads();
  for (int off = 1; off < 1024; off <<= 1) {
    float v = sm[tid];
    if (tid >= off) v += sm[tid - off];
    __syncthreads();
    sm[tid] = v;
    __syncthreads();
  }
  const float l = sm[tid];
  lfc[(size_t)bh * 1024 + tid] = l;
  const float g = icap[(size_t)bh * 1024 + tid] - l;
  garr[(size_t)bh * 1024 + tid] = g;
  __syncthreads();
  sm[tid] = g;
  __syncthreads();
  for (int off = 1; off < 1024; off <<= 1) {
    float v = sm[tid];
    if (tid >= off) v = fmaxf(v, sm[tid - off]);
    __syncthreads();
    sm[tid] = v;
    __syncthreads();
  }
  mx[(size_t)bh * 1024 + tid] = sm[tid];
}

// ---------------------------------------------------------------------------
// mLSTM core — bf16 MFMA flash-style (swapped QK^T, tr_read V).
// ---------------------------------------------------------------------------
__global__ __launch_bounds__(128) void mlstm_mfma_kernel(
    const unsigned short* __restrict__ qkb, const unsigned short* __restrict__ vb,
    const float* __restrict__ garr, const float* __restrict__ lfc,
    const float* __restrict__ mx, float* __restrict__ h) {
  __shared__ unsigned short k_lds[32 * 128];  // [s][d] chunks XOR-swizzled
  __shared__ unsigned short v_lds[32 * 256];  // [W][D][g][j][c] subtiled
  const int tid = threadIdx.x;
  const int lane = tid & 63;
  const int w = tid >> 6;
  const int bh = blockIdx.y;
  const int b = bh >> 3, hh = bh & 7;
  const int tb = blockIdx.x;
  const int fr = lane & 15, fq = lane >> 4;
  const int tw = tb * 32 + w * 16 + fr;
  const size_t tokT = (size_t)(b * SEQ + tw);
  const float scale = 0.08838834764831845f;  // 128^-0.5

  bf16x8 qf[4];
#pragma unroll
  for (int kd = 0; kd < 4; ++kd)
    qf[kd] = *(const bf16x8*)&qkb[tokT * 2048 + hh * 128 + kd * 32 + fq * 8];

  const float Mt = mx[(size_t)bh * SEQ + tw];
  const float mt = lfc[(size_t)bh * SEQ + tw] + Mt;

  f32x4 acc[16];
  const f32x4 zero = {0.f, 0.f, 0.f, 0.f};
#pragma unroll
  for (int D = 0; D < 16; ++D) acc[D] = zero;
  float asum = 0.f;

  const unsigned vbase = lds_off(v_lds);
  const int nsb = tb + 1;

  for (int sb = 0; sb < nsb; ++sb) {
    const int s0 = sb * 32;
    if (sb) __syncthreads();
#pragma unroll
    for (int it = 0; it < 4; ++it) {
      const int ck = it * 128 + tid;
      const int s = ck >> 4, c = ck & 15;
      const int cg = c ^ (s & 7);
      gload16(&qkb[(size_t)(b * SEQ + s0 + s) * 2048 + 1024 + hh * 128 + cg * 8],
              &k_lds[ck * 8]);
    }
#pragma unroll
    for (int it = 0; it < 8; ++it) {
      const int cv = it * 128 + tid;
      const int W_ = cv >> 9, D = (cv >> 5) & 15, g = (cv >> 3) & 3,
                jj = (cv >> 1) & 3, c2 = cv & 1;
      const int s = W_ * 16 + g * 4 + jj;
      gload16(&vb[(size_t)(b * SEQ + s0 + s) * 2048 + hh * 256 + D * 16 + c2 * 8],
              &v_lds[cv * 8]);
    }
    __syncthreads();

#pragma unroll
    for (int st = 0; st < 2; ++st) {
      f32x4 cfrag = zero;
      const int srow = st * 16 + fr;
#pragma unroll
      for (int kd = 0; kd < 4; ++kd) {
        const int cc = (kd * 4 + fq) ^ (srow & 7);
        const bf16x8 kf = *(const bf16x8*)&k_lds[srow * 128 + cc * 8];
        cfrag = __builtin_amdgcn_mfma_f32_16x16x32_bf16(kf, qf[kd], cfrag, 0, 0, 0);
      }
      const int sbase = s0 + st * 16 + fq * 4;
      const float4 g4 = *(const float4*)&garr[(size_t)bh * SEQ + sbase];
      float wv[4];
      wv[0] = (sbase + 0 <= tw) ? cfrag[0] * scale * __expf(g4.x - Mt) : 0.f;
      wv[1] = (sbase + 1 <= tw) ? cfrag[1] * scale * __expf(g4.y - Mt) : 0.f;
      wv[2] = (sbase + 2 <= tw) ? cfrag[2] * scale * __expf(g4.z - Mt) : 0.f;
      wv[3] = (sbase + 3 <= tw) ? cfrag[3] * scale * __expf(g4.w - Mt) : 0.f;
      asum += wv[0] + wv[1] + wv[2] + wv[3];
      bf16x4 pf;
      pf[0] = (short)f2bf(wv[0]); pf[1] = (short)f2bf(wv[1]);
      pf[2] = (short)f2bf(wv[2]); pf[3] = (short)f2bf(wv[3]);

#pragma unroll
      for (int Dg = 0; Dg < 2; ++Dg) {
        bf16x4 vf[8];
#pragma unroll
        for (int D = 0; D < 8; ++D)
          vf[D] = tr_read(vbase + (st * 4096 + (Dg * 8 + D) * 256) * 2 + lane * 8);
        asm volatile("s_waitcnt lgkmcnt(0)" ::: "memory");
        __builtin_amdgcn_sched_barrier(0);
#pragma unroll
        for (int D = 0; D < 8; ++D)
          acc[Dg * 8 + D] = mfma16_bf16(vf[D], pf, acc[Dg * 8 + D]);
      }
    }
  }

  asum += __shfl_xor(asum, 16, 64);
  asum += __shfl_xor(asum, 32, 64);
  const float n = fmaxf(fabsf(asum), __expf(-mt));
  const float inv = 1.f / (n + 1e-6f);
  asm volatile("s_nop 7\n\ts_nop 7" ::);  // MFMA->VALU guard (asm-mfma path)
  float* hrow = &h[tokT * 2048 + hh * 256];
#pragma unroll
  for (int D = 0; D < 16; ++D) {
    float4 o4;
    o4.x = acc[D][0] * inv;
    o4.y = acc[D][1] * inv;
    o4.z = acc[D][2] * inv;
    o4.w = acc[D][3] * inv;
    *(float4*)&hrow[D * 16 + fq * 4] = o4;
  }
}

// ---------------------------------------------------------------------------
// Multi-head RMS * mh_norm_w, gated by sigmoid(o_preact) -> bf16
// ---------------------------------------------------------------------------
__global__ __launch_bounds__(256) void hout_kernel(
    const float* __restrict__ h, const float* __restrict__ obuf,
    const float* __restrict__ mhw, unsigned short* __restrict__ houtb) {
  const int t = blockIdx.x;
  const int tid = threadIdx.x;
  const size_t base = (size_t)t * 2048 + tid * 8;
  float vals[8];
  *(float4*)&vals[0] = *(const float4*)&h[base];
  *(float4*)&vals[4] = *(const float4*)&h[base + 4];
  float ss = 0.f;
#pragma unroll
  for (int j = 0; j < 8; ++j) ss += vals[j] * vals[j];
#pragma unroll
  for (int m = 16; m > 0; m >>= 1) ss += __shfl_xor(ss, m, 32);
  const float rinv = rsqrtf(ss * (1.f / 256.f) + 1e-6f);
  float ov[8];
  *(float4*)&ov[0] = *(const float4*)&obuf[base];
  *(float4*)&ov[4] = *(const float4*)&obuf[base + 4];
  u16x8 res;
#pragma unroll
  for (int j = 0; j < 8; ++j) {
    const float hn = vals[j] * rinv * mhw[tid * 8 + j];
    res[j] = f2bf(hn * sigmoidf_(ov[j]));
  }
  *(u16x8*)&houtb[base] = res;
}

// ---------------------------------------------------------------------------
// out = base + w * y * rsqrt(mean(y^2)+eps); y = y0 (+ y1+y2+y3 if NY==4).
// EMIT_BF16: also write bf16 copy of out.
// ---------------------------------------------------------------------------
template <int EMIT_BF16, int NY>
__global__ __launch_bounds__(256) void addrms_kernel(
    const float* __restrict__ base_, const float* __restrict__ y0,
    const float* __restrict__ y1, const float* __restrict__ y2,
    const float* __restrict__ y3, const float* __restrict__ w,
    float* __restrict__ outp, unsigned short* __restrict__ outb) {
  const int t = blockIdx.x;
  const int tid = threadIdx.x;
  __shared__ float red[4];
  const size_t boff = (size_t)t * 2048 + tid * 8;
  float vals[8];
  *(float4*)&vals[0] = *(const float4*)&y0[boff];
  *(float4*)&vals[4] = *(const float4*)&y0[boff + 4];
  if (NY == 4) {
    float v1[8];
    *(float4*)&v1[0] = *(const float4*)&y1[boff];
    *(float4*)&v1[4] = *(const float4*)&y1[boff + 4];
#pragma unroll
    for (int j = 0; j < 8; ++j) vals[j] += v1[j];
    *(float4*)&v1[0] = *(const float4*)&y2[boff];
    *(float4*)&v1[4] = *(const float4*)&y2[boff + 4];
#pragma unroll
    for (int j = 0; j < 8; ++j) vals[j] += v1[j];
    *(float4*)&v1[0] = *(const float4*)&y3[boff];
    *(float4*)&v1[4] = *(const float4*)&y3[boff + 4];
#pragma unroll
    for (int j = 0; j < 8; ++j) vals[j] += v1[j];
  }
  float ss = 0.f;
#pragma unroll
  for (int j = 0; j < 8; ++j) ss += vals[j] * vals[j];
#pragma unroll
  for (int m = 32; m > 0; m >>= 1) ss += __shfl_xor(ss, m, 64);
  if ((tid & 63) == 0) red[tid >> 6] = ss;
  __syncthreads();
  ss = red[0] + red[1] + red[2] + red[3];
  const float rinv = rsqrtf(ss * (1.f / 2048.f) + 1e-6f);
  float bv[8];
  *(float4*)&bv[0] = *(const float4*)&base_[boff];
  *(float4*)&bv[4] = *(const float4*)&base_[boff + 4];
  float res[8];
  u16x8 rb;
#pragma unroll
  for (int j = 0; j < 8; ++j) {
    res[j] = bv[j] + vals[j] * rinv * w[tid * 8 + j];
    if (EMIT_BF16) rb[j] = f2bf(res[j]);
  }
  *(float4*)&outp[boff] = *(float4*)&res[0];
  *(float4*)&outp[boff + 4] = *(float4*)&res[4];
  if (EMIT_BF16) *(u16x8*)&outb[boff] = rb;
}

// ---------------------------------------------------------------------------
extern "C" void kernel_launch(void* const* d_in, const int* in_sizes, int n_in,
                              void* d_out, int out_size, void* d_ws,
                              size_t ws_size, hipStream_t stream) {
  const float* x = (const float*)d_in[0];
  const float* Wq = (const float*)d_in[1];
  const float* Wk = (const float*)d_in[2];
  const float* Wv = (const float*)d_in[3];
  const float* Wo = (const float*)d_in[4];
  const float* Wi = (const float*)d_in[5];
  const float* bi = (const float*)d_in[6];
  const float* Wf = (const float*)d_in[7];
  const float* bf = (const float*)d_in[8];
  const float* mhw = (const float*)d_in[9];
  const float* Wout = (const float*)d_in[10];
  const float* rms1 = (const float*)d_in[11];
  const float* Wgate = (const float*)d_in[12];
  const float* Wup = (const float*)d_in[13];
  const float* Wdown = (const float*)d_in[14];
  const float* rms2 = (const float*)d_in[15];
  float* out = (float*)d_out;
  char* base = (char*)d_ws;
  const size_t MBy = 1024 * 1024;

  // Workspace lifetime packing, peak 144 MB (MB offsets):
  //   0.. 32 W        (current transposed bf16 weights; qkvo uses 24 MB)
  //  32.. 48 obuf     (qkvo..hout)  -> actb 32..64 (after up GEMM)
  //  48.. 49 gs       (gates..mlstm; overwritten by houtb)
  //  48.. 56 houtb    (hout..attn)
  //  64.. 80 h        (mlstm..hout) -> f1 (addrms1+)
  //  80..112 gbuf     (gate..up)    -> mlp partials (down+)
  // 112..120 xb (cast..qkvo) -> f1b (addrms1..up) -> mlp2 low (down+)
  // 120..128 qkb (qkvo..mlstm) \
  // 128..136 vb  (qkvo..mlstm)  } attn 120..136 (attn..addrms1) -> mlp (down+)
  // 136..144 mlp3 hi
  unsigned short* W = (unsigned short*)(base);
  float* obuf = (float*)(base + 32 * MBy);
  unsigned short* actb = (unsigned short*)(base + 32 * MBy);
  float* gs = (float*)(base + 48 * MBy);
  unsigned short* houtb = (unsigned short*)(base + 48 * MBy);
  float* h = (float*)(base + 64 * MBy);
  float* f1 = (float*)(base + 64 * MBy);
  unsigned short* gbuf = (unsigned short*)(base + 80 * MBy);
  float* mlp = (float*)(base + 80 * MBy);  // 4 partials x 16MB: 80..144
  unsigned short* xb = (unsigned short*)(base + 112 * MBy);
  unsigned short* f1b = (unsigned short*)(base + 112 * MBy);
  unsigned short* qkb = (unsigned short*)(base + 120 * MBy);
  float* attn = (float*)(base + 120 * MBy);
  unsigned short* vb = (unsigned short*)(base + 128 * MBy);
  float* icap = gs;
  float* fls = gs + 16384;
  float* lfc = gs + 32768;
  float* garr = gs + 49152;
  float* mxp = gs + 65536;
  float* gwT = gs + 81920;  // 16x2048 fp32 transposed gate weights

  const dim3 blk(256);

  castf2b_kernel<<<TOKENS, blk, 0, stream>>>(x, xb);
  gatesT_kernel<<<128, blk, 0, stream>>>(Wi, Wf, gwT);
  gates_kernel<<<TOKENS, blk, 0, stream>>>(x, gwT, bi, bf, icap, fls);
  scan_kernel<<<16, 1024, 0, stream>>>(icap, fls, lfc, garr, mxp);

  // Fused qkvo: [qkb bf16 | vb bf16 | obuf fp32] = xb @ [Wq|Wk|Wv|Wo]
  castT_kernel<<<dim3(32, 32), blk, 0, stream>>>(Wq, W, 2048, 1024);
  castT_kernel<<<dim3(32, 32), blk, 0, stream>>>(Wk, W + (size_t)1024 * 2048,
                                                 2048, 1024);
  castT_kernel<<<dim3(64, 32), blk, 0, stream>>>(Wv, W + (size_t)2048 * 2048,
                                                 2048, 2048);
  castT_kernel<<<dim3(64, 32), blk, 0, stream>>>(Wo, W + (size_t)4096 * 2048,
                                                 2048, 2048);
  gemm256<4><<<dim3(24, 8), dim3(512), 0, stream>>>(
      xb, W, qkb, vb, obuf, nullptr, TOKENS, 6144, 2048, 2048);

  // mLSTM core (MFMA) + multi-head norm + output gate
  mlstm_mfma_kernel<<<dim3(32, 16), dim3(128), 0, stream>>>(qkb, vb, garr, lfc,
                                                            mxp, h);
  hout_kernel<<<TOKENS, blk, 0, stream>>>(h, obuf, mhw, houtb);

  // attn = houtb @ Wout (fp32 out, 128^2 kernel)
  castT_kernel<<<dim3(64, 32), blk, 0, stream>>>(Wout, W, 2048, 2048);
  gemm_bf16<0><<<dim3(16, 16), blk, 0, stream>>>(houtb, W, attn, TOKENS, 2048,
                                                 2048);

  // f1 = x + rms(attn); f1b bf16
  addrms_kernel<1, 1><<<TOKENS, blk, 0, stream>>>(
      x, attn, nullptr, nullptr, nullptr, rms1, f1, f1b);

  // MLP: gate (bf16) then up with fused silu(gate)*up epilogue
  castT_kernel<<<dim3(256, 32), blk, 0, stream>>>(Wgate, W, 2048, 8192);
  gemm256<1><<<dim3(32, 8), dim3(512), 0, stream>>>(
      f1b, W, gbuf, nullptr, nullptr, nullptr, TOKENS, 8192, 2048, 2048);
  castT_kernel<<<dim3(256, 32), blk, 0, stream>>>(Wup, W, 2048, 8192);
  gemm256<2><<<dim3(32, 8), dim3(512), 0, stream>>>(
      f1b, W, actb, nullptr, nullptr, gbuf, TOKENS, 8192, 2048, 2048);

  // down-proj, split-K=4 (fp32 partials at mlp + z*16MB)
  castT_kernel<<<dim3(64, 128), blk, 0, stream>>>(Wdown, W, 8192, 2048);
  gemm256<0><<<dim3(8, 8, 4), dim3(512), 0, stream>>>(
      actb, W, mlp, nullptr, nullptr, nullptr, TOKENS, 2048, 2048, 8192);

  // out = f1 + rms(mlp0+mlp1+mlp2+mlp3)
  addrms_kernel<0, 4><<<TOKENS, blk, 0, stream>>>(
      f1, mlp, mlp + 4194304, mlp + 8388608, mlp + 12582912, rms2, out,
      nullptr);
}

// Round 11
// 521.924 us; speedup vs baseline: 1.0512x; 1.0512x over previous
//
#include <hip/hip_runtime.h>
#include <hip/hip_bf16.h>

// B=2, S=1024, D=2048, NH=8, dqk=128, dv=256, I=8192
#define TOKENS 2048
#define DMODEL 2048
#define SEQ    1024
#define QKVO   6144   // fused q|k|v|o bf16 buffer row stride

typedef __attribute__((ext_vector_type(8))) short bf16x8;
typedef __attribute__((ext_vector_type(4))) short bf16x4;
typedef __attribute__((ext_vector_type(4))) float f32x4;
typedef __attribute__((ext_vector_type(8))) unsigned short u16x8;
typedef __attribute__((ext_vector_type(4))) unsigned short u16x4;

__device__ __forceinline__ float sigmoidf_(float x) { return 1.f / (1.f + expf(-x)); }
__device__ __forceinline__ float softcapf_(float x) { return 15.f * tanhf(x * (1.f / 15.f)); }
__device__ __forceinline__ float logsigf_(float x) {
  return (x >= 0.f) ? -log1pf(expf(-x)) : (x - log1pf(expf(x)));
}
__device__ __forceinline__ unsigned short f2bf(float f) {  // RNE, inputs finite
  unsigned u = __builtin_bit_cast(unsigned, f);
  u += 0x7FFFu + ((u >> 16) & 1u);
  return (unsigned short)(u >> 16);
}
__device__ __forceinline__ float bf2f(unsigned short b) {
  unsigned u = ((unsigned)b) << 16;
  return __builtin_bit_cast(float, u);
}

typedef __attribute__((address_space(3))) void lds_void;
typedef const __attribute__((address_space(1))) void gmem_void;
__device__ __forceinline__ void gload16(const void* g, void* l) {
  __builtin_amdgcn_global_load_lds((gmem_void*)g, (lds_void*)l, 16, 0, 0);
}
__device__ __forceinline__ unsigned lds_off(const void* p) {
  return (unsigned)(size_t)(__attribute__((address_space(3))) const void*)p;
}

#if defined(__has_builtin)
#if __has_builtin(__builtin_amdgcn_mfma_f32_16x16x16bf16_1k)
#define HAVE_MFMA16 1
#endif
#endif

__device__ __forceinline__ f32x4 mfma16_bf16(bf16x4 a, bf16x4 b, f32x4 c) {
#ifdef HAVE_MFMA16
  return __builtin_amdgcn_mfma_f32_16x16x16bf16_1k(a, b, c, 0, 0, 0);
#else
  f32x4 d;
  asm volatile("v_mfma_f32_16x16x16_bf16 %0, %1, %2, %3"
               : "=v"(d) : "v"(a), "v"(b), "v"(c));
  return d;
#endif
}

__device__ __forceinline__ bf16x4 tr_read(unsigned addr) {
  bf16x4 d;
  asm volatile("ds_read_b64_tr_b16 %0, %1" : "=v"(d) : "v"(addr));
  return d;
}

// XCD-chunked (T1) + M-fastest rasterization. Requires gridDim.x*y % 8 == 0.
__device__ __forceinline__ void remap_block(int& bm, int& bn) {
  const int nbx = gridDim.x, nby = gridDim.y;
  const int bid = blockIdx.y * nbx + blockIdx.x;
  const int q = (nbx * nby) >> 3;
  const int lid = (bid & 7) * q + (bid >> 3);
  bm = lid % nby;
  bn = lid / nby;
}

// ---------------------------------------------------------------------------
// 256x256-tile bf16 MFMA GEMM, counted-vmcnt 3-buffer pipeline (R8-proven):
// C[M,N] = A[M,K(ldk)] @ BT[N,K(ldk)]^T. BK=32, 512 thr = 8 waves (2x4),
// acc[8][4]/wave. LDS 96KB triple-buffered. Per iter: vmcnt(4) (tile t's own
// loads retired; t+1's stay in flight across the barrier) -> s_barrier ->
// stage(t+2) -> ds_read+MFMA. Never drains vmcnt to 0 in steady state.
// EPI 0: fp32 out at Cout + z*M*N (split-K partials via blockIdx.z).
// EPI 1: bf16. EPI 2: bf16 silu(aux)*acc.
// ---------------------------------------------------------------------------
template <int EPI>
__global__ __launch_bounds__(512) void gemm256(
    const unsigned short* __restrict__ A, const unsigned short* __restrict__ BT,
    void* __restrict__ Cout, const unsigned short* __restrict__ aux,
    int M, int N, int K, int ldk) {
  __shared__ unsigned short lds[3][2][8192];  // [buf][A|B][256 rows x 32 cols]
  const int tid = threadIdx.x;
  int bm, bn;
  remap_block(bm, bn);
  const int m0 = bm * 256, n0 = bn * 256;
  const int wid = tid >> 6, lane = tid & 63;
  const int wr = wid >> 2, wc = wid & 3;  // 2 x 4 waves
  const int fr = lane & 15, fq = lane >> 4;
  const size_t kz = (size_t)blockIdx.z * K;

  const f32x4 zero = {0.f, 0.f, 0.f, 0.f};
  f32x4 acc[8][4];
#pragma unroll
  for (int m = 0; m < 8; ++m)
#pragma unroll
    for (int n = 0; n < 4; ++n) acc[m][n] = zero;

  const int sr = tid >> 2;                       // row within half (0..127)
  const int sc = tid & 3;                        // linear chunk in row
  const int sgc = sc ^ ((sr + (sr >> 2)) & 3);   // pre-swizzled global chunk
  const unsigned short* Asrc = A + kz + (size_t)(m0 + sr) * ldk + sgc * 8;
  const unsigned short* Bsrc = BT + kz + (size_t)(n0 + sr) * ldk + sgc * 8;
  const size_t hstep = (size_t)128 * ldk;        // half1 row offset
  const int ldst = sr * 32 + sc * 8;             // linear LDS dest (elements)

  const int rsw = (fq ^ ((fr + (fr >> 2)) & 3)) * 8;
  const int arow0 = wr * 128 + fr;
  const int brow0 = wc * 64 + fr;

  auto stage = [&](int t) {
    const size_t ko = (size_t)t * 32;
    const int bs = t % 3;
    gload16(Asrc + ko, &lds[bs][0][ldst]);
    gload16(Asrc + ko + hstep, &lds[bs][0][4096 + ldst]);
    gload16(Bsrc + ko, &lds[bs][1][ldst]);
    gload16(Bsrc + ko + hstep, &lds[bs][1][4096 + ldst]);
  };

  const int NT = K >> 5;  // >= 2 always here
  stage(0);
  stage(1);  // 8 loads in flight

  for (int t = 0; t < NT; ++t) {
    if (t + 1 < NT) {
      asm volatile("s_waitcnt vmcnt(4)" ::: "memory");  // own tile-t loads done
    } else {
      asm volatile("s_waitcnt vmcnt(0)" ::: "memory");  // tail: drain
    }
    __builtin_amdgcn_s_barrier();      // all waves: tile t resident,
                                       // buf[(t+2)%3] consumed (iter t-1)
    if (t + 2 < NT) stage(t + 2);
    const int b = t % 3;
    const unsigned short* la = &lds[b][0][0];
    const unsigned short* lb = &lds[b][1][0];
    bf16x8 bfm[4], af[4];
#pragma unroll
    for (int n = 0; n < 4; ++n)
      bfm[n] = *(const bf16x8*)&lb[(brow0 + n * 16) * 32 + rsw];
#pragma unroll
    for (int m = 0; m < 4; ++m)
      af[m] = *(const bf16x8*)&la[(arow0 + m * 16) * 32 + rsw];
    __builtin_amdgcn_s_setprio(1);
#pragma unroll
    for (int m = 0; m < 4; ++m)
#pragma unroll
      for (int n = 0; n < 4; ++n)
        acc[m][n] = __builtin_amdgcn_mfma_f32_16x16x32_bf16(af[m], bfm[n],
                                                            acc[m][n], 0, 0, 0);
    __builtin_amdgcn_s_setprio(0);
#pragma unroll
    for (int m = 0; m < 4; ++m)
      af[m] = *(const bf16x8*)&la[(arow0 + 64 + m * 16) * 32 + rsw];
    __builtin_amdgcn_s_setprio(1);
#pragma unroll
    for (int m = 0; m < 4; ++m)
#pragma unroll
      for (int n = 0; n < 4; ++n)
        acc[4 + m][n] = __builtin_amdgcn_mfma_f32_16x16x32_bf16(
            af[m], bfm[n], acc[4 + m][n], 0, 0, 0);
    __builtin_amdgcn_s_setprio(0);
    // no trailing barrier: next iter's vmcnt+barrier orders buffer reuse
  }

  const int orow = m0 + wr * 128 + fq * 4;
  const int ocol = n0 + wc * 64 + fr;
#pragma unroll
  for (int m = 0; m < 8; ++m) {
#pragma unroll
    for (int n = 0; n < 4; ++n) {
      const int cc = ocol + n * 16;
#pragma unroll
      for (int j = 0; j < 4; ++j) {
        const int r = orow + m * 16 + j;
        float v = acc[m][n][j];
        if (EPI == 0) {
          ((float*)Cout + (size_t)blockIdx.z * M * N)[(size_t)r * N + cc] = v;
        } else if (EPI == 1) {
          ((unsigned short*)Cout)[(size_t)r * N + cc] = f2bf(v);
        } else {  // EPI 2
          const size_t idx = (size_t)r * N + cc;
          const float gv = bf2f(aux[idx]);
          ((unsigned short*)Cout)[idx] = f2bf(v * gv * sigmoidf_(gv));
        }
      }
    }
  }
}

// ---------------------------------------------------------------------------
// 128x128-tile bf16 GEMM (2-phase dbuf + swizzle) — for attn projection.
// EPI 0: fp32 out. EPI 1: bf16 out.
// ---------------------------------------------------------------------------
template <int EPI>
__global__ __launch_bounds__(256) void gemm_bf16(
    const unsigned short* __restrict__ A, const unsigned short* __restrict__ BT,
    void* __restrict__ Cout, int M, int N, int K) {
  __shared__ unsigned short As[2][128 * 32];
  __shared__ unsigned short Bs[2][128 * 32];
  const int tid = threadIdx.x;
  int bm, bn;
  remap_block(bm, bn);
  const int m0 = bm * 128;
  const int n0 = bn * 128;
  const int wid = tid >> 6;
  const int lane = tid & 63;
  const int wr = wid >> 1, wc = wid & 1;
  const int fr = lane & 15, fq = lane >> 4;

  const f32x4 zero = {0.f, 0.f, 0.f, 0.f};
  f32x4 acc[4][4];
#pragma unroll
  for (int m = 0; m < 4; ++m)
#pragma unroll
    for (int n = 0; n < 4; ++n) acc[m][n] = zero;

  const int srow = tid >> 2;
  const int sc = tid & 3;
  const int sgc = sc ^ ((srow + (srow >> 2)) & 3);
  const int scol = sgc * 8;
  const unsigned short* Ag0 = A + (size_t)(m0 + srow) * K + scol;
  const unsigned short* Ag1 = A + (size_t)(m0 + 64 + srow) * K + scol;
  const unsigned short* Bg0 = BT + (size_t)(n0 + srow) * K + scol;
  const unsigned short* Bg1 = BT + (size_t)(n0 + 64 + srow) * K + scol;
  const int rsw = (fq ^ ((fr + (fr >> 2)) & 3)) * 8;

  gload16(Ag0, &As[0][tid * 8]);
  gload16(Ag1, &As[0][2048 + tid * 8]);
  gload16(Bg0, &Bs[0][tid * 8]);
  gload16(Bg1, &Bs[0][2048 + tid * 8]);
  __syncthreads();

  const int nt = K >> 5;
  for (int t = 0; t < nt; ++t) {
    const int cur = t & 1;
    if (t + 1 < nt) {
      const int k0 = (t + 1) << 5;
      gload16(Ag0 + k0, &As[cur ^ 1][tid * 8]);
      gload16(Ag1 + k0, &As[cur ^ 1][2048 + tid * 8]);
      gload16(Bg0 + k0, &Bs[cur ^ 1][tid * 8]);
      gload16(Bg1 + k0, &Bs[cur ^ 1][2048 + tid * 8]);
    }
    bf16x8 af[4], bfm[4];
#pragma unroll
    for (int m = 0; m < 4; ++m)
      af[m] = *(const bf16x8*)&As[cur][(wr * 64 + m * 16 + fr) * 32 + rsw];
#pragma unroll
    for (int n = 0; n < 4; ++n)
      bfm[n] = *(const bf16x8*)&Bs[cur][(wc * 64 + n * 16 + fr) * 32 + rsw];
    __builtin_amdgcn_s_setprio(1);
#pragma unroll
    for (int m = 0; m < 4; ++m)
#pragma unroll
      for (int n = 0; n < 4; ++n)
        acc[m][n] = __builtin_amdgcn_mfma_f32_16x16x32_bf16(af[m], bfm[n],
                                                            acc[m][n], 0, 0, 0);
    __builtin_amdgcn_s_setprio(0);
    __syncthreads();
  }

  const int orow = m0 + wr * 64 + fq * 4;
  const int ocol = n0 + wc * 64 + fr;
#pragma unroll
  for (int m = 0; m < 4; ++m) {
#pragma unroll
    for (int n = 0; n < 4; ++n) {
      const int cc = ocol + n * 16;
#pragma unroll
      for (int j = 0; j < 4; ++j) {
        const int r = orow + m * 16 + j;
        float v = acc[m][n][j];
        if (EPI == 0) ((float*)Cout)[(size_t)r * N + cc] = v;
        else ((unsigned short*)Cout)[(size_t)r * N + cc] = f2bf(v);
      }
    }
  }
}

// ---------------------------------------------------------------------------
// fp32 -> bf16 flat cast
// ---------------------------------------------------------------------------
__global__ __launch_bounds__(256) void castf2b_kernel(
    const float* __restrict__ in, unsigned short* __restrict__ outp) {
  const size_t i = ((size_t)blockIdx.x * 256 + threadIdx.x) * 8;
  float4 a = *(const float4*)&in[i];
  float4 b = *(const float4*)&in[i + 4];
  u16x8 o;
  o[0] = f2bf(a.x); o[1] = f2bf(a.y); o[2] = f2bf(a.z); o[3] = f2bf(a.w);
  o[4] = f2bf(b.x); o[5] = f2bf(b.y); o[6] = f2bf(b.z); o[7] = f2bf(b.w);
  *(u16x8*)&outp[i] = o;
}

// ---------------------------------------------------------------------------
// fp32 [K][N] -> bf16 [N][K] transpose-cast. 128K x 64N tiles; reads are
// 256B row segments (16 lanes x float4), writes 256B (16 lanes x u16x8).
// K%128==0, N%64==0.
// ---------------------------------------------------------------------------
__global__ __launch_bounds__(256) void castT_kernel(
    const float* __restrict__ W, unsigned short* __restrict__ WT, int K, int N) {
  __shared__ float tile[128][65];
  const int n0 = blockIdx.x * 64, k0 = blockIdx.y * 128;
  const int rr = threadIdx.x >> 4;        // 0..15
  const int c4 = (threadIdx.x & 15) * 4;  // 0..60
#pragma unroll
  for (int p = 0; p < 8; ++p) {
    const int r = p * 16 + rr;
    float4 v = *(const float4*)&W[(size_t)(k0 + r) * N + n0 + c4];
    tile[r][c4 + 0] = v.x; tile[r][c4 + 1] = v.y;
    tile[r][c4 + 2] = v.z; tile[r][c4 + 3] = v.w;
  }
  __syncthreads();
  const int kc = (threadIdx.x & 15) * 8;  // k chunk 0..120
#pragma unroll
  for (int p = 0; p < 4; ++p) {
    const int n = p * 16 + rr;            // output row
    u16x8 o;
#pragma unroll
    for (int j = 0; j < 8; ++j) o[j] = f2bf(tile[kc + j][n]);
    *(u16x8*)&WT[(size_t)(n0 + n) * K + k0 + kc] = o;
  }
}

// ---------------------------------------------------------------------------
// [Wi|Wf] (each [2048][8] fp32) -> WT[16][2048] fp32 (rows: isF*8+head)
// ---------------------------------------------------------------------------
__global__ __launch_bounds__(256) void gatesT_kernel(
    const float* __restrict__ Wi, const float* __restrict__ Wf,
    float* __restrict__ WT) {
  const int idx = blockIdx.x * 256 + threadIdx.x;  // 0..32767
  const int row = idx >> 11;                       // 0..15
  const int d = idx & 2047;
  const float* W = (row < 8) ? Wi : Wf;
  WT[idx] = W[d * 8 + (row & 7)];
}

// ---------------------------------------------------------------------------
// Gate pre-activations (fp32), coalesced via WT[16][2048]
// ---------------------------------------------------------------------------
__global__ __launch_bounds__(256) void gates_kernel(
    const float* __restrict__ x, const float* __restrict__ WT,
    const float* __restrict__ bi, const float* __restrict__ bf,
    float* __restrict__ icap, float* __restrict__ fls) {
  const int t = blockIdx.x;
  const int tid = threadIdx.x;
  __shared__ float xs[2048];
  *(float4*)&xs[tid * 4] = *(const float4*)&x[(size_t)t * 2048 + tid * 4];
  *(float4*)&xs[1024 + tid * 4] =
      *(const float4*)&x[(size_t)t * 2048 + 1024 + tid * 4];
  __syncthreads();
  const int wave = tid >> 6, lane = tid & 63;
  const int b = t >> 10, s = t & 1023;
  for (int gg = wave; gg < 16; gg += 4) {
    const int head = gg & 7;
    const int isF = gg >> 3;
    const float* Wrow = WT + (size_t)gg * 2048;
    float acc = 0.f;
#pragma unroll
    for (int it = 0; it < 8; ++it) {
      const float4 w4 = *(const float4*)&Wrow[it * 256 + lane * 4];
      const float4 x4 = *(const float4*)&xs[it * 256 + lane * 4];
      acc = fmaf(x4.x, w4.x, acc);
      acc = fmaf(x4.y, w4.y, acc);
      acc = fmaf(x4.z, w4.z, acc);
      acc = fmaf(x4.w, w4.w, acc);
    }
#pragma unroll
    for (int m = 32; m > 0; m >>= 1) acc += __shfl_down(acc, m, 64);
    if (lane == 0) {
      const size_t o = (size_t)(b * 8 + head) * 1024 + s;
      if (isF) fls[o] = logsigf_(softcapf_(acc + bf[head]));
      else icap[o] = softcapf_(acc + bi[head]);
    }
  }
}

// ---------------------------------------------------------------------------
// Per-(b,h) scans: lfc = cumsum(fls); g = icap - lfc; mx = cummax(g)
// ---------------------------------------------------------------------------
__global__ __launch_bounds__(1024) void scan_kernel(
    const float* __restrict__ icap, const float* __restrict__ fls,
    float* __restrict__ lfc, float* __restrict__ garr, float* __restrict__ mx) {
  const int bh = blockIdx.x;
  const int tid = threadIdx.x;
  __shared__ float sm[1024];
  sm[tid] = fls[(size_t)bh * 1024 + tid];
  __syncthreads();
  for (int off = 1; off < 1024; off <<= 1) {
    float v = sm[tid];
    if (tid >= off) v += sm[tid - off];
    __syncthreads();
    sm[tid] = v;
    __syncthreads();
  }
  const float l = sm[tid];
  lfc[(size_t)bh * 1024 + tid] = l;
  const float g = icap[(size_t)bh * 1024 + tid] - l;
  garr[(size_t)bh * 1024 + tid] = g;
  __syncthreads();
  sm[tid] = g;
  __syncthreads();
  for (int off = 1; off < 1024; off <<= 1) {
    float v = sm[tid];
    if (tid >= off) v = fmaxf(v, sm[tid - off]);
    __syncthreads();
    sm[tid] = v;
    __syncthreads();
  }
  mx[(size_t)bh * 1024 + tid] = sm[tid];
}

// ---------------------------------------------------------------------------
// mLSTM core — bf16 MFMA flash-style (swapped QK^T, tr_read V).
// qkvob: bf16 [2048][6144]: q at h*128, k at 1024+h*128, v at 2048+h*256,
// o at 4096 (consumed by hout).
// ---------------------------------------------------------------------------
__global__ __launch_bounds__(128) void mlstm_mfma_kernel(
    const unsigned short* __restrict__ qkvob,
    const float* __restrict__ garr, const float* __restrict__ lfc,
    const float* __restrict__ mx, float* __restrict__ h) {
  __shared__ unsigned short k_lds[32 * 128];  // [s][d] chunks XOR-swizzled
  __shared__ unsigned short v_lds[32 * 256];  // [W][D][g][j][c] subtiled
  const int tid = threadIdx.x;
  const int lane = tid & 63;
  const int w = tid >> 6;
  const int bh = blockIdx.y;
  const int b = bh >> 3, hh = bh & 7;
  const int tb = blockIdx.x;
  const int fr = lane & 15, fq = lane >> 4;
  const int tw = tb * 32 + w * 16 + fr;
  const size_t tokT = (size_t)(b * SEQ + tw);
  const float scale = 0.08838834764831845f;  // 128^-0.5

  bf16x8 qf[4];
#pragma unroll
  for (int kd = 0; kd < 4; ++kd)
    qf[kd] = *(const bf16x8*)&qkvob[tokT * QKVO + hh * 128 + kd * 32 + fq * 8];

  const float Mt = mx[(size_t)bh * SEQ + tw];
  const float mt = lfc[(size_t)bh * SEQ + tw] + Mt;

  f32x4 acc[16];
  const f32x4 zero = {0.f, 0.f, 0.f, 0.f};
#pragma unroll
  for (int D = 0; D < 16; ++D) acc[D] = zero;
  float asum = 0.f;

  const unsigned vbase = lds_off(v_lds);
  const int nsb = tb + 1;

  for (int sb = 0; sb < nsb; ++sb) {
    const int s0 = sb * 32;
    if (sb) __syncthreads();
#pragma unroll
    for (int it = 0; it < 4; ++it) {
      const int ck = it * 128 + tid;
      const int s = ck >> 4, c = ck & 15;
      const int cg = c ^ (s & 7);
      gload16(&qkvob[(size_t)(b * SEQ + s0 + s) * QKVO + 1024 + hh * 128 + cg * 8],
              &k_lds[ck * 8]);
    }
#pragma unroll
    for (int it = 0; it < 8; ++it) {
      const int cv = it * 128 + tid;
      const int W_ = cv >> 9, D = (cv >> 5) & 15, g = (cv >> 3) & 3,
                jj = (cv >> 1) & 3, c2 = cv & 1;
      const int s = W_ * 16 + g * 4 + jj;
      gload16(&qkvob[(size_t)(b * SEQ + s0 + s) * QKVO + 2048 + hh * 256 +
                     D * 16 + c2 * 8],
              &v_lds[cv * 8]);
    }
    __syncthreads();

#pragma unroll
    for (int st = 0; st < 2; ++st) {
      f32x4 cfrag = zero;
      const int srow = st * 16 + fr;
#pragma unroll
      for (int kd = 0; kd < 4; ++kd) {
        const int cc = (kd * 4 + fq) ^ (srow & 7);
        const bf16x8 kf = *(const bf16x8*)&k_lds[srow * 128 + cc * 8];
        cfrag = __builtin_amdgcn_mfma_f32_16x16x32_bf16(kf, qf[kd], cfrag, 0, 0, 0);
      }
      const int sbase = s0 + st * 16 + fq * 4;
      const float4 g4 = *(const float4*)&garr[(size_t)bh * SEQ + sbase];
      float wv[4];
      wv[0] = (sbase + 0 <= tw) ? cfrag[0] * scale * __expf(g4.x - Mt) : 0.f;
      wv[1] = (sbase + 1 <= tw) ? cfrag[1] * scale * __expf(g4.y - Mt) : 0.f;
      wv[2] = (sbase + 2 <= tw) ? cfrag[2] * scale * __expf(g4.z - Mt) : 0.f;
      wv[3] = (sbase + 3 <= tw) ? cfrag[3] * scale * __expf(g4.w - Mt) : 0.f;
      asum += wv[0] + wv[1] + wv[2] + wv[3];
      bf16x4 pf;
      pf[0] = (short)f2bf(wv[0]); pf[1] = (short)f2bf(wv[1]);
      pf[2] = (short)f2bf(wv[2]); pf[3] = (short)f2bf(wv[3]);

#pragma unroll
      for (int Dg = 0; Dg < 2; ++Dg) {
        bf16x4 vf[8];
#pragma unroll
        for (int D = 0; D < 8; ++D)
          vf[D] = tr_read(vbase + (st * 4096 + (Dg * 8 + D) * 256) * 2 + lane * 8);
        asm volatile("s_waitcnt lgkmcnt(0)" ::: "memory");
        __builtin_amdgcn_sched_barrier(0);
#pragma unroll
        for (int D = 0; D < 8; ++D)
          acc[Dg * 8 + D] = mfma16_bf16(vf[D], pf, acc[Dg * 8 + D]);
      }
    }
  }

  asum += __shfl_xor(asum, 16, 64);
  asum += __shfl_xor(asum, 32, 64);
  const float n = fmaxf(fabsf(asum), __expf(-mt));
  const float inv = 1.f / (n + 1e-6f);
  asm volatile("s_nop 7\n\ts_nop 7" ::);  // MFMA->VALU guard (asm-mfma path)
  float* hrow = &h[tokT * 2048 + hh * 256];
#pragma unroll
  for (int D = 0; D < 16; ++D) {
    float4 o4;
    o4.x = acc[D][0] * inv;
    o4.y = acc[D][1] * inv;
    o4.z = acc[D][2] * inv;
    o4.w = acc[D][3] * inv;
    *(float4*)&hrow[D * 16 + fq * 4] = o4;
  }
}

// ---------------------------------------------------------------------------
// Multi-head RMS * mh_norm_w, gated by sigmoid(o_preact bf16) -> bf16
// ---------------------------------------------------------------------------
__global__ __launch_bounds__(256) void hout_kernel(
    const float* __restrict__ h, const unsigned short* __restrict__ qkvob,
    const float* __restrict__ mhw, unsigned short* __restrict__ houtb) {
  const int t = blockIdx.x;
  const int tid = threadIdx.x;
  const size_t base = (size_t)t * 2048 + tid * 8;
  float vals[8];
  *(float4*)&vals[0] = *(const float4*)&h[base];
  *(float4*)&vals[4] = *(const float4*)&h[base + 4];
  float ss = 0.f;
#pragma unroll
  for (int j = 0; j < 8; ++j) ss += vals[j] * vals[j];
#pragma unroll
  for (int m = 16; m > 0; m >>= 1) ss += __shfl_xor(ss, m, 32);
  const float rinv = rsqrtf(ss * (1.f / 256.f) + 1e-6f);
  const u16x8 ovb = *(const u16x8*)&qkvob[(size_t)t * QKVO + 4096 + tid * 8];
  u16x8 res;
#pragma unroll
  for (int j = 0; j < 8; ++j) {
    const float hn = vals[j] * rinv * mhw[tid * 8 + j];
    res[j] = f2bf(hn * sigmoidf_(bf2f(ovb[j])));
  }
  *(u16x8*)&houtb[base] = res;
}

// ---------------------------------------------------------------------------
// out = base + w * y * rsqrt(mean(y^2)+eps); y = y0 (+ y1+y2+y3 if NY==4).
// EMIT_BF16: also write bf16 copy of out.
// ---------------------------------------------------------------------------
template <int EMIT_BF16, int NY>
__global__ __launch_bounds__(256) void addrms_kernel(
    const float* __restrict__ base_, const float* __restrict__ y0,
    const float* __restrict__ y1, const float* __restrict__ y2,
    const float* __restrict__ y3, const float* __restrict__ w,
    float* __restrict__ outp, unsigned short* __restrict__ outb) {
  const int t = blockIdx.x;
  const int tid = threadIdx.x;
  __shared__ float red[4];
  const size_t boff = (size_t)t * 2048 + tid * 8;
  float vals[8];
  *(float4*)&vals[0] = *(const float4*)&y0[boff];
  *(float4*)&vals[4] = *(const float4*)&y0[boff + 4];
  if (NY == 4) {
    float v1[8];
    *(float4*)&v1[0] = *(const float4*)&y1[boff];
    *(float4*)&v1[4] = *(const float4*)&y1[boff + 4];
#pragma unroll
    for (int j = 0; j < 8; ++j) vals[j] += v1[j];
    *(float4*)&v1[0] = *(const float4*)&y2[boff];
    *(float4*)&v1[4] = *(const float4*)&y2[boff + 4];
#pragma unroll
    for (int j = 0; j < 8; ++j) vals[j] += v1[j];
    *(float4*)&v1[0] = *(const float4*)&y3[boff];
    *(float4*)&v1[4] = *(const float4*)&y3[boff + 4];
#pragma unroll
    for (int j = 0; j < 8; ++j) vals[j] += v1[j];
  }
  float ss = 0.f;
#pragma unroll
  for (int j = 0; j < 8; ++j) ss += vals[j] * vals[j];
#pragma unroll
  for (int m = 32; m > 0; m >>= 1) ss += __shfl_xor(ss, m, 64);
  if ((tid & 63) == 0) red[tid >> 6] = ss;
  __syncthreads();
  ss = red[0] + red[1] + red[2] + red[3];
  const float rinv = rsqrtf(ss * (1.f / 2048.f) + 1e-6f);
  float bv[8];
  *(float4*)&bv[0] = *(const float4*)&base_[boff];
  *(float4*)&bv[4] = *(const float4*)&base_[boff + 4];
  float res[8];
  u16x8 rb;
#pragma unroll
  for (int j = 0; j < 8; ++j) {
    res[j] = bv[j] + vals[j] * rinv * w[tid * 8 + j];
    if (EMIT_BF16) rb[j] = f2bf(res[j]);
  }
  *(float4*)&outp[boff] = *(float4*)&res[0];
  *(float4*)&outp[boff + 4] = *(float4*)&res[4];
  if (EMIT_BF16) *(u16x8*)&outb[boff] = rb;
}

// ---------------------------------------------------------------------------
extern "C" void kernel_launch(void* const* d_in, const int* in_sizes, int n_in,
                              void* d_out, int out_size, void* d_ws,
                              size_t ws_size, hipStream_t stream) {
  const float* x = (const float*)d_in[0];
  const float* Wq = (const float*)d_in[1];
  const float* Wk = (const float*)d_in[2];
  const float* Wv = (const float*)d_in[3];
  const float* Wo = (const float*)d_in[4];
  const float* Wi = (const float*)d_in[5];
  const float* bi = (const float*)d_in[6];
  const float* Wf = (const float*)d_in[7];
  const float* bf = (const float*)d_in[8];
  const float* mhw = (const float*)d_in[9];
  const float* Wout = (const float*)d_in[10];
  const float* rms1 = (const float*)d_in[11];
  const float* Wgate = (const float*)d_in[12];
  const float* Wup = (const float*)d_in[13];
  const float* Wdown = (const float*)d_in[14];
  const float* rms2 = (const float*)d_in[15];
  float* out = (float*)d_out;
  char* base = (char*)d_ws;
  const size_t MBy = 1024 * 1024;

  // Workspace lifetime packing, peak 144 MB (MB offsets):
  //   0.. 32 W       (current transposed bf16 weights; qkvo uses 24 MB)
  //  32.. 64 actb    (after up GEMM; region free before that)
  //  48.. 49 gs      (gates..mlstm; dead before houtb) + gwT
  //  48.. 56 houtb   (hout..attn)  [overwrites gs after mlstm]
  //  64.. 80 h       (mlstm..hout) -> f1 (addrms1+)
  //  80..112 gbuf    (gate..up)    -> mlp partials 80..144 (down+)
  // 112..120 xb (cast..qkvo) -> f1b (addrms1..up)
  // 120..144 qkvob bf16 (qkvo..hout) -> attn fp32 120..136 (attn..addrms1)
  unsigned short* W = (unsigned short*)(base);
  unsigned short* actb = (unsigned short*)(base + 32 * MBy);
  float* gs = (float*)(base + 48 * MBy);
  unsigned short* houtb = (unsigned short*)(base + 48 * MBy);
  float* h = (float*)(base + 64 * MBy);
  float* f1 = (float*)(base + 64 * MBy);
  unsigned short* gbuf = (unsigned short*)(base + 80 * MBy);
  float* mlp = (float*)(base + 80 * MBy);  // 4 partials x 16MB: 80..144
  unsigned short* xb = (unsigned short*)(base + 112 * MBy);
  unsigned short* f1b = (unsigned short*)(base + 112 * MBy);
  unsigned short* qkvob = (unsigned short*)(base + 120 * MBy);
  float* attn = (float*)(base + 120 * MBy);
  float* icap = gs;
  float* fls = gs + 16384;
  float* lfc = gs + 32768;
  float* garr = gs + 49152;
  float* mxp = gs + 65536;
  float* gwT = gs + 81920;  // 16x2048 fp32 transposed gate weights

  const dim3 blk(256);

  castf2b_kernel<<<TOKENS, blk, 0, stream>>>(x, xb);
  gatesT_kernel<<<128, blk, 0, stream>>>(Wi, Wf, gwT);
  gates_kernel<<<TOKENS, blk, 0, stream>>>(x, gwT, bi, bf, icap, fls);
  scan_kernel<<<16, 1024, 0, stream>>>(icap, fls, lfc, garr, mxp);

  // Fused qkvo: qkvob bf16 [2048][6144] = xb @ [Wq|Wk|Wv|Wo]
  castT_kernel<<<dim3(16, 16), blk, 0, stream>>>(Wq, W, 2048, 1024);
  castT_kernel<<<dim3(16, 16), blk, 0, stream>>>(Wk, W + (size_t)1024 * 2048,
                                                 2048, 1024);
  castT_kernel<<<dim3(32, 16), blk, 0, stream>>>(Wv, W + (size_t)2048 * 2048,
                                                 2048, 2048);
  castT_kernel<<<dim3(32, 16), blk, 0, stream>>>(Wo, W + (size_t)4096 * 2048,
                                                 2048, 2048);
  gemm256<1><<<dim3(24, 8), dim3(512), 0, stream>>>(
      xb, W, qkvob, nullptr, TOKENS, 6144, 2048, 2048);

  // mLSTM core (MFMA) + multi-head norm + output gate
  mlstm_mfma_kernel<<<dim3(32, 16), dim3(128), 0, stream>>>(qkvob, garr, lfc,
                                                            mxp, h);
  hout_kernel<<<TOKENS, blk, 0, stream>>>(h, qkvob, mhw, houtb);

  // attn = houtb @ Wout (fp32 out, 128^2 kernel)
  castT_kernel<<<dim3(32, 16), blk, 0, stream>>>(Wout, W, 2048, 2048);
  gemm_bf16<0><<<dim3(16, 16), blk, 0, stream>>>(houtb, W, attn, TOKENS, 2048,
                                                 2048);

  // f1 = x + rms(attn); f1b bf16
  addrms_kernel<1, 1><<<TOKENS, blk, 0, stream>>>(
      x, attn, nullptr, nullptr, nullptr, rms1, f1, f1b);

  // MLP: gate (bf16) then up with fused silu(gate)*up epilogue
  castT_kernel<<<dim3(128, 16), blk, 0, stream>>>(Wgate, W, 2048, 8192);
  gemm256<1><<<dim3(32, 8), dim3(512), 0, stream>>>(
      f1b, W, gbuf, nullptr, TOKENS, 8192, 2048, 2048);
  castT_kernel<<<dim3(128, 16), blk, 0, stream>>>(Wup, W, 2048, 8192);
  gemm256<2><<<dim3(32, 8), dim3(512), 0, stream>>>(
      f1b, W, actb, gbuf, TOKENS, 8192, 2048, 2048);

  // down-proj, split-K=4 (fp32 partials at mlp + z*16MB)
  castT_kernel<<<dim3(32, 64), blk, 0, stream>>>(Wdown, W, 8192, 2048);
  gemm256<0><<<dim3(8, 8, 4), dim3(512), 0, stream>>>(
      actb, W, mlp, nullptr, TOKENS, 2048, 2048, 8192);

  // out = f1 + rms(mlp0+mlp1+mlp2+mlp3)
  addrms_kernel<0, 4><<<TOKENS, blk, 0, stream>>>(
      f1, mlp, mlp + 4194304, mlp + 8388608, mlp + 12582912, rms2, out,
      nullptr);
}